// Round 4
// baseline (1034.778 us; speedup 1.0000x reference)
//
#include <hip/hip_runtime.h>

#define BB_ 4
#define TT_ 8
#define CC_ 64
#define HW 4096
#define UMAP 1024      // floats per (b,c) spectrum map: 32 ky * 16 kx * 2
#define STEP 0.09817477042468103f   // 2*pi/64

// ws float offsets
#define OFF_UXALL 0                                     // 8*256*1024
#define OFF_UH    (OFF_UXALL + TT_*256*UMAP)            // 256*1024
#define OFF_URH   (OFF_UH + 256*UMAP)                   // 256*1024
#define OFF_SX    (OFF_URH + 256*UMAP)                  // 3 slots * 8 t * 256 maps * 1024
#define OFF_SPART (OFF_SX + 3*TT_*256*UMAP)             // 2 slots * 8 ic * 256 maps * 1024
#define OFF_H     (OFF_SPART + 2*8*256*UMAP)
#define OFF_Z     (OFF_H + BB_*CC_*HW)
#define OFF_RH    (OFF_Z + BB_*CC_*HW)
#define OFF_PH    (OFF_RH + BB_*CC_*HW)

// ---------------- init: h = bias, Uh = spectrum of constant map ----------------
__global__ __launch_bounds__(256) void k_init(float* __restrict__ hb,
                                              float* __restrict__ Uh,
                                              const float* __restrict__ bias_h) {
    float v = bias_h[0];
    int blk = blockIdx.x;
    if (blk < 1024) {
        int idx = (blk * 256 + threadIdx.x) * 4;
        *(float4*)(hb + idx) = make_float4(v, v, v, v);
    } else {
        // spectrum of constant v map: only (ky=0,kx=0) = 4096*v/64 = 64*v
        int map = blk - 1024;
        float4 z = make_float4(0.f, 0.f, 0.f, 0.f);
        if (threadIdx.x == 0) z.x = 64.f * v;
        *(float4*)(Uh + (size_t)map * UMAP + threadIdx.x * 4) = z;
    }
}

// ---------------- forward partial DFT stages (input already in LDS su[64*65]) ----
__device__ __forceinline__ void dft_stages(const float* __restrict__ su,
                                           float* __restrict__ FxR, float* __restrict__ FxI,
                                           float* __restrict__ dst) {
    int tid = threadIdx.x;
    int kx = tid & 15, yb = tid >> 4;
    float stc, sts;
    __sincosf(-STEP * (float)kx, &sts, &stc);
    float wr = 1.f, wi = 0.f;
    float aR[4] = {0, 0, 0, 0}, aI[4] = {0, 0, 0, 0};
    for (int x = 0; x < 64; x++) {
        #pragma unroll
        for (int j = 0; j < 4; j++) {
            float v = su[(yb + 16 * j) * 65 + x];
            aR[j] = fmaf(v, wr, aR[j]);
            aI[j] = fmaf(v, wi, aI[j]);
        }
        float t = wr * stc - wi * sts;
        wi = wr * sts + wi * stc;
        wr = t;
    }
    #pragma unroll
    for (int j = 0; j < 4; j++) {
        FxR[(yb + 16 * j) * 16 + kx] = aR[j];
        FxI[(yb + 16 * j) * 16 + kx] = aI[j];
    }
    __syncthreads();
    int kb = tid >> 4;
    float c0, s0, c1, s1;
    __sincosf(-STEP * (float)kb, &s0, &c0);
    __sincosf(-STEP * (float)(kb + 48), &s1, &c1);
    float w0r = 1, w0i = 0, w1r = 1, w1i = 0;
    float A0r = 0, A0i = 0, A1r = 0, A1i = 0;
    for (int y = 0; y < 64; y++) {
        float Fr = FxR[y * 16 + kx], Fi = FxI[y * 16 + kx];
        A0r = fmaf(Fr, w0r, A0r); A0r = fmaf(-Fi, w0i, A0r);
        A0i = fmaf(Fr, w0i, A0i); A0i = fmaf(Fi, w0r, A0i);
        A1r = fmaf(Fr, w1r, A1r); A1r = fmaf(-Fi, w1i, A1r);
        A1i = fmaf(Fr, w1i, A1i); A1i = fmaf(Fi, w1r, A1i);
        float t0 = w0r * c0 - w0i * s0; w0i = w0r * s0 + w0i * c0; w0r = t0;
        float t1 = w1r * c1 - w1i * s1; w1i = w1r * s1 + w1i * c1; w1r = t1;
    }
    const float sc = 1.f / 64.f;
    float2* d2 = (float2*)dst;
    d2[kb * 16 + kx]        = make_float2(A0r * sc, A0i * sc);
    d2[(kb + 16) * 16 + kx] = make_float2(A1r * sc, A1i * sc);
}

// ---------------- batched DFT of all x_t maps (once per launch) ----------------
__global__ __launch_bounds__(256) void k_dft_x(const float* __restrict__ x,
                                               float* __restrict__ Uxall) {
    __shared__ float su[64 * 65];
    __shared__ float FxR[1024], FxI[1024];
    int blk = blockIdx.x;
    int t = blk >> 8, map = blk & 255;
    int b = map >> 6, c = map & 63;
    const float* src = x + (((size_t)b * TT_ + t) * CC_ + c) * HW;
    int tid = threadIdx.x;
    #pragma unroll
    for (int k = 0; k < 4; k++) {
        int off = k * 1024 + tid * 4;
        float4 v = *(const float4*)(src + off);
        int y = off >> 6, xx = off & 63;
        su[y * 65 + xx + 0] = v.x; su[y * 65 + xx + 1] = v.y;
        su[y * 65 + xx + 2] = v.z; su[y * 65 + xx + 3] = v.w;
    }
    __syncthreads();
    dft_stages(su, FxR, FxI, Uxall + ((size_t)t * 256 + map) * UMAP);
}

// ---------------- mix accumulation core: 2-deep software pipeline ---------------
#define MIX_FMA_BLOCK                                                     \
    {                                                                     \
        float2 uu[4] = {u0, u1, u2, u3};                                  \
        float2 ww[4] = {w0, w1, w2, w3};                                  \
        _Pragma("unroll")                                                 \
        for (int oo = 0; oo < 4; oo++) {                                  \
            _Pragma("unroll")                                             \
            for (int bb = 0; bb < 4; bb++) {                              \
                aR[oo][bb] = fmaf(uu[bb].x, ww[oo].x, aR[oo][bb]);        \
                aR[oo][bb] = fmaf(-uu[bb].y, ww[oo].y, aR[oo][bb]);       \
                aI[oo][bb] = fmaf(uu[bb].x, ww[oo].y, aI[oo][bb]);        \
                aI[oo][bb] = fmaf(uu[bb].y, ww[oo].x, aI[oo][bb]);        \
            }                                                             \
        }                                                                 \
    }

__device__ __forceinline__ void mix_accum(const float2* __restrict__ W2,
                                          const float2* __restrict__ U2,
                                          int niter,
                                          float aR[4][4], float aI[4][4])
{
    float2 w0 = W2[0], w1 = W2[256], w2 = W2[512], w3 = W2[768];
    float2 u0 = U2[0], u1 = U2[32768], u2 = U2[65536], u3 = U2[98304];
    for (int i = 1; i < niter; i++) {
        W2 += 16384; U2 += 512;
        float2 nw0 = W2[0], nw1 = W2[256], nw2 = W2[512], nw3 = W2[768];
        float2 nu0 = U2[0], nu1 = U2[32768], nu2 = U2[65536], nu3 = U2[98304];
        MIX_FMA_BLOCK
        w0 = nw0; w1 = nw1; w2 = nw2; w3 = nw3;
        u0 = nu0; u1 = nu1; u2 = nu2; u3 = nu3;
    }
    MIX_FMA_BLOCK
}

// ---------------- upfront: all x-side mixes (layers 0,2,4, all t) ---------------
// blk bits: [li(3)][t(8)][half(2)][og(16)]; full 64-i accumulation, no partials.
// Sx layout: [(li*8+t)*256 + b*64+o][UMAP]
__global__ __launch_bounds__(256) void k_mix_x(
    const float* __restrict__ Uxall,
    const float* __restrict__ sw1, const float* __restrict__ sw2,
    float* __restrict__ Sx)
{
    int blk = blockIdx.x;
    int og = blk & 15;
    int half = (blk >> 4) & 1;
    int t = (blk >> 5) & 7;
    int li = blk >> 8;          // 0,1,2 -> layers 0,2,4
    int l = li * 2;
    int m = threadIdx.x;
    int o0 = og * 4;
    const float2* wt = (const float2*)(half ? sw2 : sw1);
    const float2* W2 = wt + (((size_t)l * 64) * 64 + o0) * 256 + m;
    const float2* U2 = (const float2*)Uxall + ((size_t)t * 256) * 512 + half * 256 + m;
    float aR[4][4], aI[4][4];
    #pragma unroll
    for (int oo = 0; oo < 4; oo++)
        #pragma unroll
        for (int b = 0; b < 4; b++) { aR[oo][b] = 0.f; aI[oo][b] = 0.f; }
    mix_accum(W2, U2, 64, aR, aI);
    float2* S2 = (float2*)Sx;
    #pragma unroll
    for (int oo = 0; oo < 4; oo++)
        #pragma unroll
        for (int b = 0; b < 4; b++)
            S2[((size_t)(li * 8 + t) * 256 + b * 64 + o0 + oo) * 512 + half * 256 + m]
                = make_float2(aR[oo][b], aI[oo][b]);
}

// ---------------- per-step h-side mix body --------------------------------------
// blk bits: [g][half][ic(8)][og(16)]; 8 i per block.
// Spart layout: [(g*8+ic)*256 + b*64+o][UMAP]
__device__ __forceinline__ void mix_body_h(int blk, int l0, int l1,
    const float* __restrict__ U,
    const float* __restrict__ sw1, const float* __restrict__ sw2,
    float* __restrict__ Spart)
{
    int og = blk & 15;
    int ic = (blk >> 4) & 7;
    int half = (blk >> 7) & 1;
    int g = (blk >> 8) & 1;
    int m = threadIdx.x;
    int o0 = og * 4, ib = ic * 8;
    int l = g ? l1 : l0;
    const float2* wt = (const float2*)(half ? sw2 : sw1);
    const float2* W2 = wt + (((size_t)l * 64 + ib) * 64 + o0) * 256 + m;
    const float2* U2 = (const float2*)U + (size_t)ib * 512 + half * 256 + m;
    float aR[4][4], aI[4][4];
    #pragma unroll
    for (int oo = 0; oo < 4; oo++)
        #pragma unroll
        for (int b = 0; b < 4; b++) { aR[oo][b] = 0.f; aI[oo][b] = 0.f; }
    mix_accum(W2, U2, 8, aR, aI);
    float2* S2 = (float2*)Spart;
    #pragma unroll
    for (int oo = 0; oo < 4; oo++)
        #pragma unroll
        for (int b = 0; b < 4; b++)
            S2[((size_t)(g * 8 + ic) * 256 + b * 64 + o0 + oo) * 512 + half * 256 + m]
                = make_float2(aR[oo][b], aI[oo][b]);
}

// ---------------- 1x1-conv skip (shared-body) ----------------------------------
__device__ __forceinline__ void skip_body(int blk, float* sA, float* sB,
    const float* __restrict__ uA, long long bsA,
    const float* __restrict__ uB, long long bsB,
    const float* __restrict__ skw,
    int lA0, int lB0, int lA1, int lB1,
    const float* __restrict__ gate_b, int g0, int g1,
    float* __restrict__ out0, float* __restrict__ out1)
{
    int g = blk >> 8;
    int r = blk & 255;
    int b = r >> 6, tile = r & 63;
    int tid = threadIdx.x;
    int o = tid & 63, wv = tid >> 6;
    int pxb = tile * 64 + wv * 16;
    int lA = g ? lA1 : lA0;
    int lB = g ? lB1 : lB0;
    for (int n = 0; n < 16; n++) {
        int idx = n * 256 + tid;
        sA[idx] = skw[lA * 4096 + idx];
        sB[idx] = skw[lB * 4096 + idx];
    }
    __syncthreads();
    float acc[16];
    #pragma unroll
    for (int k = 0; k < 16; k++) acc[k] = 0.f;
    const float* pa = uA + (long long)b * bsA + pxb;
    const float* pb = uB + (long long)b * bsB + pxb;
    for (int i = 0; i < 64; i++) {
        float wa = sA[i * 64 + o];
        float wb2 = sB[i * 64 + o];
        const float4* qa = (const float4*)(pa + i * HW);
        const float4* qb = (const float4*)(pb + i * HW);
        #pragma unroll
        for (int q = 0; q < 4; q++) {
            float4 va = qa[q], vb = qb[q];
            acc[4 * q + 0] = fmaf(wa, va.x, acc[4 * q + 0]);
            acc[4 * q + 0] = fmaf(wb2, vb.x, acc[4 * q + 0]);
            acc[4 * q + 1] = fmaf(wa, va.y, acc[4 * q + 1]);
            acc[4 * q + 1] = fmaf(wb2, vb.y, acc[4 * q + 1]);
            acc[4 * q + 2] = fmaf(wa, va.z, acc[4 * q + 2]);
            acc[4 * q + 2] = fmaf(wb2, vb.z, acc[4 * q + 2]);
            acc[4 * q + 3] = fmaf(wa, va.w, acc[4 * q + 3]);
            acc[4 * q + 3] = fmaf(wb2, vb.w, acc[4 * q + 3]);
        }
    }
    float gb = gate_b[g ? g1 : g0];
    float* outp = (g ? out1 : out0) + ((long long)b * 64 + o) * HW + pxb;
    #pragma unroll
    for (int k = 0; k < 16; k++) outp[k] = acc[k] + gb;
}

// ---------------- fused front kernels: h-side mix + skip ------------------------
__global__ __launch_bounds__(256) void k_front_zr(
    const float* __restrict__ Uh,
    const float* __restrict__ xt, const float* __restrict__ hb,
    const float* __restrict__ sw1, const float* __restrict__ sw2,
    const float* __restrict__ skw, const float* __restrict__ gate_b,
    float* __restrict__ Spart, float* __restrict__ zb, float* __restrict__ rhb)
{
    __shared__ float smem[8192];
    int blk = blockIdx.x;
    if (blk < 512) {
        mix_body_h(blk, 1, 3, Uh, sw1, sw2, Spart);
    } else {
        skip_body(blk - 512, smem, smem + 4096,
                  xt, (long long)TT_ * CC_ * HW, hb, (long long)CC_ * HW,
                  skw, 0, 1, 2, 3, gate_b, 0, 1, zb, rhb);
    }
}

__global__ __launch_bounds__(256) void k_front_h(
    const float* __restrict__ Urh,
    const float* __restrict__ xt, const float* __restrict__ rhb,
    const float* __restrict__ sw1, const float* __restrict__ sw2,
    const float* __restrict__ skw, const float* __restrict__ gate_b,
    float* __restrict__ Spart, float* __restrict__ phb)
{
    __shared__ float smem[8192];
    int blk = blockIdx.x;
    if (blk < 256) {
        mix_body_h(blk, 5, 5, Urh, sw1, sw2, Spart);
    } else {
        skip_body(blk - 256, smem, smem + 4096,
                  xt, (long long)TT_ * CC_ * HW, rhb, (long long)CC_ * HW,
                  skw, 4, 5, 4, 5, gate_b, 2, 2, phb, phb);
    }
}

// ---------------- inverse DFT stage 1 (shared) ----------------------------------
__device__ __forceinline__ void idft_stage1(const float* __restrict__ SR,
                                            const float* __restrict__ SI,
                                            float* __restrict__ GR, float* __restrict__ GI)
{
    int tid = threadIdx.x;
    int kx = tid & 15, yb = tid >> 4;
    #pragma unroll
    for (int j = 0; j < 4; j++) {
        int y = yb + 16 * j;
        float stc, sts;
        __sincosf(STEP * (float)y, &sts, &stc);
        float ar = 0.f, ai = 0.f;
        float wr = 1.f, wi = 0.f;
        for (int k = 0; k < 16; k++) {
            float sr_ = SR[k * 16 + kx], si_ = SI[k * 16 + kx];
            ar = fmaf(sr_, wr, ar); ar = fmaf(-si_, wi, ar);
            ai = fmaf(sr_, wi, ai); ai = fmaf(si_, wr, ai);
            float t = wr * stc - wi * sts; wi = wr * sts + wi * stc; wr = t;
        }
        int q = (3 * y) & 3;
        float w2r = (q == 0) ? 1.f : ((q == 2) ? -1.f : 0.f);
        float w2i = (q == 1) ? 1.f : ((q == 3) ? -1.f : 0.f);
        for (int k = 16; k < 32; k++) {
            float sr_ = SR[k * 16 + kx], si_ = SI[k * 16 + kx];
            ar = fmaf(sr_, w2r, ar); ar = fmaf(-si_, w2i, ar);
            ai = fmaf(sr_, w2i, ai); ai = fmaf(si_, w2r, ai);
            float t = w2r * stc - w2i * sts; w2i = w2r * sts + w2i * stc; w2r = t;
        }
        GR[y * 16 + kx] = ar;
        GI[y * 16 + kx] = ai;
    }
}

// ---------------- back kernel zr: idft + gate epilogue + fused rh forward DFT ---
__global__ __launch_bounds__(256) void k_back_zr(
    const float* __restrict__ Spart, const float* __restrict__ Sx, int t,
    float* __restrict__ zb, float* __restrict__ rhb,
    const float* __restrict__ hb, float* __restrict__ Urh)
{
    __shared__ float smem[6208];
    float* SR = smem;          // 512
    float* SI = smem + 512;    // 512
    float* GR = smem + 1024;   // 1024
    float* GI = smem + 2048;   // 1024
    int g = blockIdx.x >> 8;
    int map = blockIdx.x & 255;
    int tid = threadIdx.x;
    {
        float4 v = ((const float4*)Sx)[((size_t)(g * 8 + t) * 256 + map) * 256 + tid];
        float sxr = v.x, sxi = v.y, syr = v.z, syi = v.w;
        const float4* base = (const float4*)Spart;
        #pragma unroll
        for (int ic = 0; ic < 8; ic++) {
            float4 p = base[((size_t)(g * 8 + ic) * 256 + map) * 256 + tid];
            sxr += p.x; sxi += p.y; syr += p.z; syi += p.w;
        }
        SR[2 * tid] = sxr; SI[2 * tid] = sxi;
        SR[2 * tid + 1] = syr; SI[2 * tid + 1] = syi;
    }
    __syncthreads();
    idft_stage1(SR, SI, GR, GI);
    __syncthreads();
    int x = tid & 63, ybase = tid >> 6;
    float cx, sx;
    __sincosf(STEP * (float)x, &sx, &cx);
    size_t mo = (size_t)map * HW;
    float rhv[16];
    #pragma unroll
    for (int j = 0; j < 16; j++) {
        int y = ybase + 4 * j;
        float acc = GR[y * 16];
        float wr = cx, wi = sx;
        #pragma unroll
        for (int k = 1; k < 16; k++) {
            acc = fmaf(2.f * GR[y * 16 + k], wr, acc);
            acc = fmaf(-2.f * GI[y * 16 + k], wi, acc);
            float t2 = wr * cx - wi * sx; wi = wr * sx + wi * cx; wr = t2;
        }
        float val = acc * (1.f / 64.f);
        int idx = y * 64 + x;
        if (g == 0) {
            float pre = val + zb[mo + idx];
            zb[mo + idx] = 1.f / (1.f + __expf(-pre));
        } else {
            float pre = val + rhb[mo + idx];
            float rr = 1.f / (1.f + __expf(-pre));
            float rh = rr * hb[mo + idx];
            rhb[mo + idx] = rh;
            rhv[j] = rh;
        }
    }
    if (g == 0) return;
    __syncthreads();
    float* su = smem;
    #pragma unroll
    for (int j = 0; j < 16; j++) {
        int y = ybase + 4 * j;
        su[y * 65 + x] = rhv[j];
    }
    __syncthreads();
    dft_stages(su, smem + 4160, smem + 5184, Urh + (size_t)map * UMAP);
}

// ---------------- back kernel h: idft + GRU update + fused h forward DFT --------
__global__ __launch_bounds__(256) void k_back_h(
    const float* __restrict__ Spart, const float* __restrict__ Sx, int t,
    const float* __restrict__ zb, const float* __restrict__ phb,
    float* __restrict__ hb, float* __restrict__ Uh)
{
    __shared__ float smem[6208];
    float* SR = smem;
    float* SI = smem + 512;
    float* GR = smem + 1024;
    float* GI = smem + 2048;
    int map = blockIdx.x & 255;
    int tid = threadIdx.x;
    {
        float4 v = ((const float4*)Sx)[((size_t)(2 * 8 + t) * 256 + map) * 256 + tid];
        float sxr = v.x, sxi = v.y, syr = v.z, syi = v.w;
        const float4* base = (const float4*)Spart;
        #pragma unroll
        for (int ic = 0; ic < 8; ic++) {
            float4 p = base[((size_t)ic * 256 + map) * 256 + tid];
            sxr += p.x; sxi += p.y; syr += p.z; syi += p.w;
        }
        SR[2 * tid] = sxr; SI[2 * tid] = sxi;
        SR[2 * tid + 1] = syr; SI[2 * tid + 1] = syi;
    }
    __syncthreads();
    idft_stage1(SR, SI, GR, GI);
    __syncthreads();
    int x = tid & 63, ybase = tid >> 6;
    float cx, sx;
    __sincosf(STEP * (float)x, &sx, &cx);
    size_t mo = (size_t)map * HW;
    float hv[16];
    #pragma unroll
    for (int j = 0; j < 16; j++) {
        int y = ybase + 4 * j;
        float acc = GR[y * 16];
        float wr = cx, wi = sx;
        #pragma unroll
        for (int k = 1; k < 16; k++) {
            acc = fmaf(2.f * GR[y * 16 + k], wr, acc);
            acc = fmaf(-2.f * GI[y * 16 + k], wi, acc);
            float t2 = wr * cx - wi * sx; wi = wr * sx + wi * cx; wr = t2;
        }
        float val = acc * (1.f / 64.f);
        int idx = y * 64 + x;
        float pre = val + phb[mo + idx];
        float hh = (pre > 0.f) ? 1.0507009873554805f * pre
                               : 1.7580993408473766f * (__expf(pre) - 1.f);
        float z = zb[mo + idx];
        float hn = fmaf(z, hh - hb[mo + idx], hb[mo + idx]);
        hb[mo + idx] = hn;
        hv[j] = hn;
    }
    __syncthreads();
    float* su = smem;
    #pragma unroll
    for (int j = 0; j < 16; j++) {
        int y = ybase + 4 * j;
        su[y * 65 + x] = hv[j];
    }
    __syncthreads();
    dft_stages(su, smem + 4160, smem + 5184, Uh + (size_t)map * UMAP);
}

extern "C" void kernel_launch(void* const* d_in, const int* in_sizes, int n_in,
                              void* d_out, int out_size, void* d_ws, size_t ws_size,
                              hipStream_t stream)
{
    (void)in_sizes; (void)n_in; (void)out_size; (void)ws_size;
    const float* x   = (const float*)d_in[0];
    const float* sw1 = (const float*)d_in[1];
    const float* sw2 = (const float*)d_in[2];
    const float* skw = (const float*)d_in[3];
    const float* gb  = (const float*)d_in[4];
    const float* bh  = (const float*)d_in[5];
    float* ws    = (float*)d_ws;
    float* Uxall = ws + OFF_UXALL;
    float* Uh    = ws + OFF_UH;
    float* Urh   = ws + OFF_URH;
    float* Sx    = ws + OFF_SX;
    float* Sp    = ws + OFF_SPART;
    float* hb    = ws + OFF_H;
    float* zb    = ws + OFF_Z;
    float* rhb   = ws + OFF_RH;
    float* phb   = ws + OFF_PH;

    k_init<<<1280, 256, 0, stream>>>(hb, Uh, bh);
    k_dft_x<<<2048, 256, 0, stream>>>(x, Uxall);
    k_mix_x<<<768, 256, 0, stream>>>(Uxall, sw1, sw2, Sx);
    for (int t = 0; t < TT_; t++) {
        const float* xt = x + (size_t)t * CC_ * HW;
        k_front_zr<<<1024, 256, 0, stream>>>(Uh, xt, hb, sw1, sw2, skw, gb,
                                             Sp, zb, rhb);
        k_back_zr<<<512, 256, 0, stream>>>(Sp, Sx, t, zb, rhb, hb, Urh);
        k_front_h<<<512, 256, 0, stream>>>(Urh, xt, rhb, sw1, sw2, skw, gb,
                                           Sp, phb);
        k_back_h<<<256, 256, 0, stream>>>(Sp, Sx, t, zb, phb, hb, Uh);
    }
    hipMemcpyAsync(d_out, hb, (size_t)BB_ * CC_ * HW * sizeof(float),
                   hipMemcpyDeviceToDevice, stream);
}

// Round 5
// 875.991 us; speedup vs baseline: 1.1813x; 1.1813x over previous
//
#include <hip/hip_runtime.h>

#define BB_ 4
#define TT_ 8
#define CC_ 64
#define HW 4096
#define UMAP 1024      // floats per (b,c) spectrum map: 32 ky * 16 kx * 2
#define STEP 0.09817477042468103f   // 2*pi/64

// ws float offsets
#define OFF_UXALL 0                                     // 8*256*1024
#define OFF_UH    (OFF_UXALL + TT_*256*UMAP)            // 256*1024
#define OFF_URH   (OFF_UH + 256*UMAP)                   // 256*1024
#define OFF_SX    (OFF_URH + 256*UMAP)                  // 3 slots * 8 t * 256 maps * 1024
#define OFF_SPART (OFF_SX + 3*TT_*256*UMAP)             // 2 slots * 8 ic * 256 maps * 1024
#define OFF_H     (OFF_SPART + 2*8*256*UMAP)
#define OFF_Z     (OFF_H + BB_*CC_*HW)
#define OFF_RH    (OFF_Z + BB_*CC_*HW)
#define OFF_PH    (OFF_RH + BB_*CC_*HW)

// ---------------- init: h = bias, Uh = spectrum of constant map ----------------
__global__ __launch_bounds__(256) void k_init(float* __restrict__ hb,
                                              float* __restrict__ Uh,
                                              const float* __restrict__ bias_h) {
    float v = bias_h[0];
    int blk = blockIdx.x;
    if (blk < 1024) {
        int idx = (blk * 256 + threadIdx.x) * 4;
        *(float4*)(hb + idx) = make_float4(v, v, v, v);
    } else {
        // spectrum of constant v map: only (ky=0,kx=0) = 4096*v/64 = 64*v
        int map = blk - 1024;
        float4 z = make_float4(0.f, 0.f, 0.f, 0.f);
        if (threadIdx.x == 0) z.x = 64.f * v;
        *(float4*)(Uh + (size_t)map * UMAP + threadIdx.x * 4) = z;
    }
}

// ---------------- forward partial DFT stages (input already in LDS su[64*65]) ----
__device__ __forceinline__ void dft_stages(const float* __restrict__ su,
                                           float* __restrict__ FxR, float* __restrict__ FxI,
                                           float* __restrict__ dst) {
    int tid = threadIdx.x;
    int kx = tid & 15, yb = tid >> 4;
    float stc, sts;
    __sincosf(-STEP * (float)kx, &sts, &stc);
    float wr = 1.f, wi = 0.f;
    float aR[4] = {0, 0, 0, 0}, aI[4] = {0, 0, 0, 0};
    for (int x = 0; x < 64; x++) {
        #pragma unroll
        for (int j = 0; j < 4; j++) {
            float v = su[(yb + 16 * j) * 65 + x];
            aR[j] = fmaf(v, wr, aR[j]);
            aI[j] = fmaf(v, wi, aI[j]);
        }
        float t = wr * stc - wi * sts;
        wi = wr * sts + wi * stc;
        wr = t;
    }
    #pragma unroll
    for (int j = 0; j < 4; j++) {
        FxR[(yb + 16 * j) * 16 + kx] = aR[j];
        FxI[(yb + 16 * j) * 16 + kx] = aI[j];
    }
    __syncthreads();
    int kb = tid >> 4;
    float c0, s0, c1, s1;
    __sincosf(-STEP * (float)kb, &s0, &c0);
    __sincosf(-STEP * (float)(kb + 48), &s1, &c1);
    float w0r = 1, w0i = 0, w1r = 1, w1i = 0;
    float A0r = 0, A0i = 0, A1r = 0, A1i = 0;
    for (int y = 0; y < 64; y++) {
        float Fr = FxR[y * 16 + kx], Fi = FxI[y * 16 + kx];
        A0r = fmaf(Fr, w0r, A0r); A0r = fmaf(-Fi, w0i, A0r);
        A0i = fmaf(Fr, w0i, A0i); A0i = fmaf(Fi, w0r, A0i);
        A1r = fmaf(Fr, w1r, A1r); A1r = fmaf(-Fi, w1i, A1r);
        A1i = fmaf(Fr, w1i, A1i); A1i = fmaf(Fi, w1r, A1i);
        float t0 = w0r * c0 - w0i * s0; w0i = w0r * s0 + w0i * c0; w0r = t0;
        float t1 = w1r * c1 - w1i * s1; w1i = w1r * s1 + w1i * c1; w1r = t1;
    }
    const float sc = 1.f / 64.f;
    float2* d2 = (float2*)dst;
    d2[kb * 16 + kx]        = make_float2(A0r * sc, A0i * sc);
    d2[(kb + 16) * 16 + kx] = make_float2(A1r * sc, A1i * sc);
}

// ---------------- batched DFT of all x_t maps (once per launch) ----------------
__global__ __launch_bounds__(256) void k_dft_x(const float* __restrict__ x,
                                               float* __restrict__ Uxall) {
    __shared__ float su[64 * 65];
    __shared__ float FxR[1024], FxI[1024];
    int blk = blockIdx.x;
    int t = blk >> 8, map = blk & 255;
    int b = map >> 6, c = map & 63;
    const float* src = x + (((size_t)b * TT_ + t) * CC_ + c) * HW;
    int tid = threadIdx.x;
    #pragma unroll
    for (int k = 0; k < 4; k++) {
        int off = k * 1024 + tid * 4;
        float4 v = *(const float4*)(src + off);
        int y = off >> 6, xx = off & 63;
        su[y * 65 + xx + 0] = v.x; su[y * 65 + xx + 1] = v.y;
        su[y * 65 + xx + 2] = v.z; su[y * 65 + xx + 3] = v.w;
    }
    __syncthreads();
    dft_stages(su, FxR, FxI, Uxall + ((size_t)t * 256 + map) * UMAP);
}

// ---------------- mix accumulation core: depth-3 software pipeline --------------
__device__ __forceinline__ void mix_load(const float2* __restrict__ W2,
                                         const float2* __restrict__ U2, int i,
                                         float2 w[4], float2 u[4]) {
    const float2* wp = W2 + (size_t)i * 16384;
    const float2* up = U2 + (size_t)i * 512;
    w[0] = wp[0]; w[1] = wp[256]; w[2] = wp[512]; w[3] = wp[768];
    u[0] = up[0]; u[1] = up[32768]; u[2] = up[65536]; u[3] = up[98304];
}

__device__ __forceinline__ void mix_fma(const float2 w[4], const float2 u[4],
                                        float aR[4][4], float aI[4][4]) {
    #pragma unroll
    for (int oo = 0; oo < 4; oo++)
        #pragma unroll
        for (int bb = 0; bb < 4; bb++) {
            aR[oo][bb] = fmaf(u[bb].x, w[oo].x, aR[oo][bb]);
            aR[oo][bb] = fmaf(-u[bb].y, w[oo].y, aR[oo][bb]);
            aI[oo][bb] = fmaf(u[bb].x, w[oo].y, aI[oo][bb]);
            aI[oo][bb] = fmaf(u[bb].y, w[oo].x, aI[oo][bb]);
        }
}

// niter must be even and >= 4 (we use 8 and 64)
__device__ __forceinline__ void mix_accum(const float2* __restrict__ W2,
                                          const float2* __restrict__ U2,
                                          int niter, float aR[4][4], float aI[4][4])
{
    float2 wA[4], uA[4], wB[4], uB[4], wN[4], uN[4];
    mix_load(W2, U2, 0, wA, uA);
    mix_load(W2, U2, 1, wB, uB);
    for (int i = 0; i + 2 < niter; i += 2) {
        mix_load(W2, U2, i + 2, wN, uN);
        mix_fma(wA, uA, aR, aI);
        #pragma unroll
        for (int k = 0; k < 4; k++) { wA[k] = wN[k]; uA[k] = uN[k]; }
        mix_load(W2, U2, i + 3, wN, uN);
        mix_fma(wB, uB, aR, aI);
        #pragma unroll
        for (int k = 0; k < 4; k++) { wB[k] = wN[k]; uB[k] = uN[k]; }
    }
    mix_fma(wA, uA, aR, aI);
    mix_fma(wB, uB, aR, aI);
}

// ---------------- upfront: all x-side mixes (layers 0,2,4, all t) ---------------
// blk bits: [li(3)][t(8)][half(2)][og(16)]; full 64-i accumulation, no partials.
// Sx layout: [(li*8+t)*256 + b*64+o][UMAP]
__global__ __launch_bounds__(256) void k_mix_x(
    const float* __restrict__ Uxall,
    const float* __restrict__ sw1, const float* __restrict__ sw2,
    float* __restrict__ Sx)
{
    int blk = blockIdx.x;
    int og = blk & 15;
    int half = (blk >> 4) & 1;
    int t = (blk >> 5) & 7;
    int li = blk >> 8;          // 0,1,2 -> layers 0,2,4
    int l = li * 2;
    int m = threadIdx.x;
    int o0 = og * 4;
    const float2* wt = (const float2*)(half ? sw2 : sw1);
    const float2* W2 = wt + (((size_t)l * 64) * 64 + o0) * 256 + m;
    const float2* U2 = (const float2*)Uxall + ((size_t)t * 256) * 512 + half * 256 + m;
    float aR[4][4], aI[4][4];
    #pragma unroll
    for (int oo = 0; oo < 4; oo++)
        #pragma unroll
        for (int b = 0; b < 4; b++) { aR[oo][b] = 0.f; aI[oo][b] = 0.f; }
    mix_accum(W2, U2, 64, aR, aI);
    float2* S2 = (float2*)Sx;
    #pragma unroll
    for (int oo = 0; oo < 4; oo++)
        #pragma unroll
        for (int b = 0; b < 4; b++)
            S2[((size_t)(li * 8 + t) * 256 + b * 64 + o0 + oo) * 512 + half * 256 + m]
                = make_float2(aR[oo][b], aI[oo][b]);
}

// ---------------- per-step h-side mix body --------------------------------------
// blk bits: [g][half][ic(8)][og(16)]; 8 i per block.
// Spart layout: [(g*8+ic)*256 + b*64+o][UMAP]
__device__ __forceinline__ void mix_body_h(int blk, int l0, int l1,
    const float* __restrict__ U,
    const float* __restrict__ sw1, const float* __restrict__ sw2,
    float* __restrict__ Spart)
{
    int og = blk & 15;
    int ic = (blk >> 4) & 7;
    int half = (blk >> 7) & 1;
    int g = (blk >> 8) & 1;
    int m = threadIdx.x;
    int o0 = og * 4, ib = ic * 8;
    int l = g ? l1 : l0;
    const float2* wt = (const float2*)(half ? sw2 : sw1);
    const float2* W2 = wt + (((size_t)l * 64 + ib) * 64 + o0) * 256 + m;
    const float2* U2 = (const float2*)U + (size_t)ib * 512 + half * 256 + m;
    float aR[4][4], aI[4][4];
    #pragma unroll
    for (int oo = 0; oo < 4; oo++)
        #pragma unroll
        for (int b = 0; b < 4; b++) { aR[oo][b] = 0.f; aI[oo][b] = 0.f; }
    mix_accum(W2, U2, 8, aR, aI);
    float2* S2 = (float2*)Spart;
    #pragma unroll
    for (int oo = 0; oo < 4; oo++)
        #pragma unroll
        for (int b = 0; b < 4; b++)
            S2[((size_t)(g * 8 + ic) * 256 + b * 64 + o0 + oo) * 512 + half * 256 + m]
                = make_float2(aR[oo][b], aI[oo][b]);
}

// ---------------- 1x1-conv skip v2: lane <-> pixel, LDS weights -----------------
// r bits: [b(2)][otile(2)][pxt(4)] (256 blocks per gate). Thread: 1 px, 16 o acc.
// out[b, o0+k, px] = sum_i uA[b,i,px] skw[lA][i,o0+k] + uB[b,i,px] skw[lB][i,o0+k] + gb
__device__ __forceinline__ void skip_v2(int r, float* __restrict__ sW,
    const float* __restrict__ uA, long long bsA,
    const float* __restrict__ uB, long long bsB,
    const float* __restrict__ skw, int lA, int lB, float gb,
    float* __restrict__ out)
{
    int pxt = r & 15, ot = (r >> 4) & 3, b = r >> 6;
    int tid = threadIdx.x;
    int px = pxt * 256 + tid;
    int o0 = ot * 16;
    // stage sW[p][i][k]: p=layer(2), i=64, k=16  (2048 floats)
    for (int n = 0; n < 8; n++) {
        int idx = n * 256 + tid;
        int p = idx >> 10, i = (idx >> 4) & 63, k = idx & 15;
        sW[idx] = skw[(p ? lB : lA) * 4096 + i * 64 + o0 + k];
    }
    __syncthreads();
    float acc[16];
    #pragma unroll
    for (int k = 0; k < 16; k++) acc[k] = 0.f;
    const float* pa = uA + (long long)b * bsA + px;
    const float* pb = uB + (long long)b * bsB + px;
    const float4* sA4 = (const float4*)sW;            // [64][4] float4
    const float4* sB4 = (const float4*)(sW + 1024);
    #pragma unroll 4
    for (int i = 0; i < 64; i++) {
        float ua = pa[(size_t)i * HW];
        float ub = pb[(size_t)i * HW];
        #pragma unroll
        for (int q = 0; q < 4; q++) {
            float4 wa = sA4[i * 4 + q];
            float4 wb = sB4[i * 4 + q];
            acc[4 * q + 0] = fmaf(ua, wa.x, acc[4 * q + 0]);
            acc[4 * q + 0] = fmaf(ub, wb.x, acc[4 * q + 0]);
            acc[4 * q + 1] = fmaf(ua, wa.y, acc[4 * q + 1]);
            acc[4 * q + 1] = fmaf(ub, wb.y, acc[4 * q + 1]);
            acc[4 * q + 2] = fmaf(ua, wa.z, acc[4 * q + 2]);
            acc[4 * q + 2] = fmaf(ub, wb.z, acc[4 * q + 2]);
            acc[4 * q + 3] = fmaf(ua, wa.w, acc[4 * q + 3]);
            acc[4 * q + 3] = fmaf(ub, wb.w, acc[4 * q + 3]);
        }
    }
    float* op = out + ((long long)b * 64 + o0) * HW + px;
    #pragma unroll
    for (int k = 0; k < 16; k++) op[(size_t)k * HW] = acc[k] + gb;
}

// ---------------- fused front kernels: h-side mix + skip ------------------------
__global__ __launch_bounds__(256) void k_front_zr(
    const float* __restrict__ Uh,
    const float* __restrict__ xt, const float* __restrict__ hb,
    const float* __restrict__ sw1, const float* __restrict__ sw2,
    const float* __restrict__ skw, const float* __restrict__ gate_b,
    float* __restrict__ Spart, float* __restrict__ zb, float* __restrict__ rhb)
{
    __shared__ float smem[2048];
    int blk = blockIdx.x;
    if (blk < 512) {
        mix_body_h(blk, 1, 3, Uh, sw1, sw2, Spart);
    } else {
        int r = blk - 512;
        int g = r >> 8;
        skip_v2(r & 255, smem,
                xt, (long long)TT_ * CC_ * HW, hb, (long long)CC_ * HW,
                skw, g ? 2 : 0, g ? 3 : 1, gate_b[g], g ? rhb : zb);
    }
}

__global__ __launch_bounds__(256) void k_front_h(
    const float* __restrict__ Urh,
    const float* __restrict__ xt, const float* __restrict__ rhb,
    const float* __restrict__ sw1, const float* __restrict__ sw2,
    const float* __restrict__ skw, const float* __restrict__ gate_b,
    float* __restrict__ Spart, float* __restrict__ phb)
{
    __shared__ float smem[2048];
    int blk = blockIdx.x;
    if (blk < 256) {
        mix_body_h(blk, 5, 5, Urh, sw1, sw2, Spart);
    } else {
        int r = blk - 256;
        skip_v2(r, smem,
                xt, (long long)TT_ * CC_ * HW, rhb, (long long)CC_ * HW,
                skw, 4, 5, gate_b[2], phb);
    }
}

// ---------------- inverse DFT stage 1 (shared) ----------------------------------
__device__ __forceinline__ void idft_stage1(const float* __restrict__ SR,
                                            const float* __restrict__ SI,
                                            float* __restrict__ GR, float* __restrict__ GI)
{
    int tid = threadIdx.x;
    int kx = tid & 15, yb = tid >> 4;
    #pragma unroll
    for (int j = 0; j < 4; j++) {
        int y = yb + 16 * j;
        float stc, sts;
        __sincosf(STEP * (float)y, &sts, &stc);
        float ar = 0.f, ai = 0.f;
        float wr = 1.f, wi = 0.f;
        for (int k = 0; k < 16; k++) {
            float sr_ = SR[k * 16 + kx], si_ = SI[k * 16 + kx];
            ar = fmaf(sr_, wr, ar); ar = fmaf(-si_, wi, ar);
            ai = fmaf(sr_, wi, ai); ai = fmaf(si_, wr, ai);
            float t = wr * stc - wi * sts; wi = wr * sts + wi * stc; wr = t;
        }
        int q = (3 * y) & 3;
        float w2r = (q == 0) ? 1.f : ((q == 2) ? -1.f : 0.f);
        float w2i = (q == 1) ? 1.f : ((q == 3) ? -1.f : 0.f);
        for (int k = 16; k < 32; k++) {
            float sr_ = SR[k * 16 + kx], si_ = SI[k * 16 + kx];
            ar = fmaf(sr_, w2r, ar); ar = fmaf(-si_, w2i, ar);
            ai = fmaf(sr_, w2i, ai); ai = fmaf(si_, w2r, ai);
            float t = w2r * stc - w2i * sts; w2i = w2r * sts + w2i * stc; w2r = t;
        }
        GR[y * 16 + kx] = ar;
        GI[y * 16 + kx] = ai;
    }
}

// ---------------- back kernel zr: idft + gate epilogue + fused rh forward DFT ---
__global__ __launch_bounds__(256) void k_back_zr(
    const float* __restrict__ Spart, const float* __restrict__ Sx, int t,
    float* __restrict__ zb, float* __restrict__ rhb,
    const float* __restrict__ hb, float* __restrict__ Urh)
{
    __shared__ float smem[6208];
    float* SR = smem;          // 512
    float* SI = smem + 512;    // 512
    float* GR = smem + 1024;   // 1024
    float* GI = smem + 2048;   // 1024
    int g = blockIdx.x >> 8;
    int map = blockIdx.x & 255;
    int tid = threadIdx.x;
    {
        float4 v = ((const float4*)Sx)[((size_t)(g * 8 + t) * 256 + map) * 256 + tid];
        float sxr = v.x, sxi = v.y, syr = v.z, syi = v.w;
        const float4* base = (const float4*)Spart;
        #pragma unroll
        for (int ic = 0; ic < 8; ic++) {
            float4 p = base[((size_t)(g * 8 + ic) * 256 + map) * 256 + tid];
            sxr += p.x; sxi += p.y; syr += p.z; syi += p.w;
        }
        SR[2 * tid] = sxr; SI[2 * tid] = sxi;
        SR[2 * tid + 1] = syr; SI[2 * tid + 1] = syi;
    }
    __syncthreads();
    idft_stage1(SR, SI, GR, GI);
    __syncthreads();
    int x = tid & 63, ybase = tid >> 6;
    float cx, sx;
    __sincosf(STEP * (float)x, &sx, &cx);
    size_t mo = (size_t)map * HW;
    float rhv[16];
    #pragma unroll
    for (int j = 0; j < 16; j++) {
        int y = ybase + 4 * j;
        float acc = GR[y * 16];
        float wr = cx, wi = sx;
        #pragma unroll
        for (int k = 1; k < 16; k++) {
            acc = fmaf(2.f * GR[y * 16 + k], wr, acc);
            acc = fmaf(-2.f * GI[y * 16 + k], wi, acc);
            float t2 = wr * cx - wi * sx; wi = wr * sx + wi * cx; wr = t2;
        }
        float val = acc * (1.f / 64.f);
        int idx = y * 64 + x;
        if (g == 0) {
            float pre = val + zb[mo + idx];
            zb[mo + idx] = 1.f / (1.f + __expf(-pre));
        } else {
            float pre = val + rhb[mo + idx];
            float rr = 1.f / (1.f + __expf(-pre));
            float rh = rr * hb[mo + idx];
            rhb[mo + idx] = rh;
            rhv[j] = rh;
        }
    }
    if (g == 0) return;
    __syncthreads();
    float* su = smem;
    #pragma unroll
    for (int j = 0; j < 16; j++) {
        int y = ybase + 4 * j;
        su[y * 65 + x] = rhv[j];
    }
    __syncthreads();
    dft_stages(su, smem + 4160, smem + 5184, Urh + (size_t)map * UMAP);
}

// ---------------- back kernel h: idft + GRU update + fused h forward DFT --------
__global__ __launch_bounds__(256) void k_back_h(
    const float* __restrict__ Spart, const float* __restrict__ Sx, int t,
    const float* __restrict__ zb, const float* __restrict__ phb,
    float* __restrict__ hb, float* __restrict__ Uh)
{
    __shared__ float smem[6208];
    float* SR = smem;
    float* SI = smem + 512;
    float* GR = smem + 1024;
    float* GI = smem + 2048;
    int map = blockIdx.x & 255;
    int tid = threadIdx.x;
    {
        float4 v = ((const float4*)Sx)[((size_t)(2 * 8 + t) * 256 + map) * 256 + tid];
        float sxr = v.x, sxi = v.y, syr = v.z, syi = v.w;
        const float4* base = (const float4*)Spart;
        #pragma unroll
        for (int ic = 0; ic < 8; ic++) {
            float4 p = base[((size_t)ic * 256 + map) * 256 + tid];
            sxr += p.x; sxi += p.y; syr += p.z; syi += p.w;
        }
        SR[2 * tid] = sxr; SI[2 * tid] = sxi;
        SR[2 * tid + 1] = syr; SI[2 * tid + 1] = syi;
    }
    __syncthreads();
    idft_stage1(SR, SI, GR, GI);
    __syncthreads();
    int x = tid & 63, ybase = tid >> 6;
    float cx, sx;
    __sincosf(STEP * (float)x, &sx, &cx);
    size_t mo = (size_t)map * HW;
    float hv[16];
    #pragma unroll
    for (int j = 0; j < 16; j++) {
        int y = ybase + 4 * j;
        float acc = GR[y * 16];
        float wr = cx, wi = sx;
        #pragma unroll
        for (int k = 1; k < 16; k++) {
            acc = fmaf(2.f * GR[y * 16 + k], wr, acc);
            acc = fmaf(-2.f * GI[y * 16 + k], wi, acc);
            float t2 = wr * cx - wi * sx; wi = wr * sx + wi * cx; wr = t2;
        }
        float val = acc * (1.f / 64.f);
        int idx = y * 64 + x;
        float pre = val + phb[mo + idx];
        float hh = (pre > 0.f) ? 1.0507009873554805f * pre
                               : 1.7580993408473766f * (__expf(pre) - 1.f);
        float z = zb[mo + idx];
        float hn = fmaf(z, hh - hb[mo + idx], hb[mo + idx]);
        hb[mo + idx] = hn;
        hv[j] = hn;
    }
    __syncthreads();
    float* su = smem;
    #pragma unroll
    for (int j = 0; j < 16; j++) {
        int y = ybase + 4 * j;
        su[y * 65 + x] = hv[j];
    }
    __syncthreads();
    dft_stages(su, smem + 4160, smem + 5184, Uh + (size_t)map * UMAP);
}

extern "C" void kernel_launch(void* const* d_in, const int* in_sizes, int n_in,
                              void* d_out, int out_size, void* d_ws, size_t ws_size,
                              hipStream_t stream)
{
    (void)in_sizes; (void)n_in; (void)out_size; (void)ws_size;
    const float* x   = (const float*)d_in[0];
    const float* sw1 = (const float*)d_in[1];
    const float* sw2 = (const float*)d_in[2];
    const float* skw = (const float*)d_in[3];
    const float* gb  = (const float*)d_in[4];
    const float* bh  = (const float*)d_in[5];
    float* ws    = (float*)d_ws;
    float* Uxall = ws + OFF_UXALL;
    float* Uh    = ws + OFF_UH;
    float* Urh   = ws + OFF_URH;
    float* Sx    = ws + OFF_SX;
    float* Sp    = ws + OFF_SPART;
    float* hb    = ws + OFF_H;
    float* zb    = ws + OFF_Z;
    float* rhb   = ws + OFF_RH;
    float* phb   = ws + OFF_PH;

    k_init<<<1280, 256, 0, stream>>>(hb, Uh, bh);
    k_dft_x<<<2048, 256, 0, stream>>>(x, Uxall);
    k_mix_x<<<768, 256, 0, stream>>>(Uxall, sw1, sw2, Sx);
    for (int t = 0; t < TT_; t++) {
        const float* xt = x + (size_t)t * CC_ * HW;
        k_front_zr<<<1024, 256, 0, stream>>>(Uh, xt, hb, sw1, sw2, skw, gb,
                                             Sp, zb, rhb);
        k_back_zr<<<512, 256, 0, stream>>>(Sp, Sx, t, zb, rhb, hb, Urh);
        k_front_h<<<512, 256, 0, stream>>>(Urh, xt, rhb, sw1, sw2, skw, gb,
                                           Sp, phb);
        k_back_h<<<256, 256, 0, stream>>>(Sp, Sx, t, zb, phb, hb, Uh);
    }
    hipMemcpyAsync(d_out, hb, (size_t)BB_ * CC_ * HW * sizeof(float),
                   hipMemcpyDeviceToDevice, stream);
}